// Round 3
// baseline (7981.154 us; speedup 1.0000x reference)
//
#include <hip/hip_runtime.h>

#define B_ 128
#define T_ 256
#define H_ 1024
#define BT_ (B_*T_)

typedef _Float16 h16;
typedef _Float16 v8h __attribute__((ext_vector_type(8)));
typedef float v4f __attribute__((ext_vector_type(4)));

// ---- workspace layout (bytes) ----
#define OFF_BAR   0
#define OFF_B0    256
#define OFF_B1    4352
#define OFF_H0B0  8448
#define OFF_H0B1  (OFF_H0B0 + B_*H_*2)
#define OFF_H1B0  (OFF_H0B1 + B_*H_*2)
#define OFF_H1B1  (OFF_H1B0 + B_*H_*2)
#define OFF_WI0T  (OFF_H1B1 + B_*H_*2)            // H*H fp16 = 2 MB
#define OFF_XH    (OFF_WI0T + H_*H_*2)             // BT*H fp16 = 64 MB
#define OFF_XP    (OFF_XH + (size_t)BT_*H_*2)      // BT*H fp16 = 64 MB
// total ~131 MB

#define MFMA16(a,b,c) __builtin_amdgcn_mfma_f32_16x16x32_f16((a),(b),(c),0,0,0)

__device__ __forceinline__ float fast_tanh(float x) {
  float e = __expf(2.0f * x);
  return 1.0f - __fdividef(2.0f, e + 1.0f);   // saturates correctly at +/-1
}

// device-scope grid barrier: bar[0]=count, bar[1]=generation (memset to 0 each launch)
__device__ __forceinline__ void gridbar(unsigned* bar, unsigned nwg) {
  __syncthreads();
  if (threadIdx.x == 0) {
    __threadfence();  // release: make this wg's h-state stores device-visible
    unsigned g = __hip_atomic_load(&bar[1], __ATOMIC_RELAXED, __HIP_MEMORY_SCOPE_AGENT);
    unsigned a = __hip_atomic_fetch_add(&bar[0], 1u, __ATOMIC_ACQ_REL, __HIP_MEMORY_SCOPE_AGENT);
    if (a == nwg - 1u) {
      __hip_atomic_store(&bar[0], 0u, __ATOMIC_RELAXED, __HIP_MEMORY_SCOPE_AGENT);
      __hip_atomic_fetch_add(&bar[1], 1u, __ATOMIC_ACQ_REL, __HIP_MEMORY_SCOPE_AGENT);
    } else {
      while (__hip_atomic_load(&bar[1], __ATOMIC_RELAXED, __HIP_MEMORY_SCOPE_AGENT) == g) {
        __builtin_amdgcn_s_sleep(1);
      }
      (void)__hip_atomic_load(&bar[1], __ATOMIC_ACQUIRE, __HIP_MEMORY_SCOPE_AGENT); // acquire: inv caches
    }
  }
  __syncthreads();
}

// ---- prep: x (f32) -> fp16 ----
__global__ void k_prep_x(const float* __restrict__ x, h16* __restrict__ xh) {
  int i = blockIdx.x * 256 + threadIdx.x;      // one v8h per thread
  const float4* xin = (const float4*)x;
  float4 f0 = xin[i * 2], f1 = xin[i * 2 + 1];
  v8h o;
  o[0]=(h16)f0.x; o[1]=(h16)f0.y; o[2]=(h16)f0.z; o[3]=(h16)f0.w;
  o[4]=(h16)f1.x; o[5]=(h16)f1.y; o[6]=(h16)f1.z; o[7]=(h16)f1.w;
  ((v8h*)xh)[i] = o;
}

// ---- prep: fused biases b0 = bi0+bh0, b1 = bi1+bh1 ----
__global__ void k_prep_bias(const float* __restrict__ bi, const float* __restrict__ bh,
                            float* __restrict__ b0, float* __restrict__ b1) {
  int i = blockIdx.x * 256 + threadIdx.x;   // 0..2047
  float v = bi[i] + bh[i];
  if (i < H_) b0[i] = v; else b1[i - H_] = v;
}

// ---- prep: Wi0T[n][k] = (fp16) Wi0[k][n] ----
__global__ void k_prep_wt(const float* __restrict__ W, h16* __restrict__ WT) {
  __shared__ float tile[64][65];
  int bx = blockIdx.x & 15, by = blockIdx.x >> 4;
  int tid = threadIdx.x;
  int c = tid & 63, r4 = tid >> 6;
#pragma unroll
  for (int i = 0; i < 16; i++) { int r = i * 4 + r4; tile[r][c] = W[(by*64 + r)*H_ + bx*64 + c]; }
  __syncthreads();
#pragma unroll
  for (int i = 0; i < 16; i++) { int rr = i * 4 + r4; WT[(bx*64 + rr)*H_ + by*64 + c] = (h16)tile[c][rr]; }
}

// ---- Xp = xh @ Wi0  (A row-major [BT][H] fp16, B via Wi0T [n][k]) -> fp16 [BT][H]
__global__ __launch_bounds__(256) void k_xp_gemm(const h16* __restrict__ xh,
                                                 const h16* __restrict__ wt,
                                                 h16* __restrict__ xp) {
  int w = threadIdx.x >> 6, l = threadIdx.x & 63;
  int lm = l & 15, kg = l >> 4;
  int wgM = blockIdx.x & 255, wgN = blockIdx.x >> 8;
  int mbase = wgM * 128 + w * 32;
  int nbase = wgN * 64;

  v4f acc[2][4];
#pragma unroll
  for (int a = 0; a < 2; a++)
#pragma unroll
    for (int b = 0; b < 4; b++) acc[a][b] = (v4f){0.f,0.f,0.f,0.f};

  const v8h* A0 = (const v8h*)xh + (mbase + lm) * 128 + kg;          // +4 per kstep
  const v8h* A1 = A0 + 16 * 128;
  const v8h* Bp0 = (const v8h*)wt + (nbase +  0 + lm) * 128 + kg;
  const v8h* Bp1 = (const v8h*)wt + (nbase + 16 + lm) * 128 + kg;
  const v8h* Bp2 = (const v8h*)wt + (nbase + 32 + lm) * 128 + kg;
  const v8h* Bp3 = (const v8h*)wt + (nbase + 48 + lm) * 128 + kg;

#pragma unroll 4
  for (int ks = 0; ks < 32; ks++) {
    v8h a0 = A0[ks * 4], a1 = A1[ks * 4];
    v8h b0 = Bp0[ks * 4], b1 = Bp1[ks * 4], b2 = Bp2[ks * 4], b3 = Bp3[ks * 4];
    acc[0][0] = MFMA16(a0, b0, acc[0][0]);  acc[1][0] = MFMA16(a1, b0, acc[1][0]);
    acc[0][1] = MFMA16(a0, b1, acc[0][1]);  acc[1][1] = MFMA16(a1, b1, acc[1][1]);
    acc[0][2] = MFMA16(a0, b2, acc[0][2]);  acc[1][2] = MFMA16(a1, b2, acc[1][2]);
    acc[0][3] = MFMA16(a0, b3, acc[0][3]);  acc[1][3] = MFMA16(a1, b3, acc[1][3]);
  }
#pragma unroll
  for (int mi = 0; mi < 2; mi++)
#pragma unroll
    for (int ni = 0; ni < 4; ni++)
#pragma unroll
      for (int r = 0; r < 4; r++) {
        int row = mbase + mi * 16 + kg * 4 + r;      // D: row = 4*(lane>>4)+reg
        int col = nbase + ni * 16 + lm;              // D: col = lane&15
        xp[row * H_ + col] = (h16)acc[mi][ni][r];
      }
}

// ---- persistent scan over T with grid barriers ----
// 128 wgs = 64 col-blocks (16 cols) x 2 row-halves (64 rows). Weights slices in LDS.
__global__ __launch_bounds__(256) void k_scan(const float* __restrict__ wi,
                                              const float* __restrict__ wh,
                                              const float* __restrict__ h0in,
                                              const h16* __restrict__ xp,
                                              const float* __restrict__ b0v,
                                              const float* __restrict__ b1v,
                                              h16* __restrict__ hbase,
                                              float* __restrict__ out,
                                              unsigned* __restrict__ bar) {
  __shared__ h16 wlds[3 * 16 * 1024];   // 96 KB: Wh0 | Wi1 | Wh1 column slices, swizzled
  const int tid = threadIdx.x;
  const int j  = blockIdx.x >> 1;       // col block (16 cols)
  const int mh = blockIdx.x & 1;        // row half (64 rows)
  const int w  = tid >> 6, l = tid & 63;
  const int lm = l & 15, kg = l >> 4;

  // --- one-time LDS weight fill (transpose+convert+swizzle from row-major f32 W[k][n]) ---
  const float* mats[3] = { wh, wi + H_ * H_, wh + H_ * H_ };   // Wh0, Wi1, Wh1
  for (int m = 0; m < 3; m++) {
    const float* src = mats[m] + j * 16;
    char* base = (char*)wlds + m * 32768;
    for (int it = 0; it < 64; it++) {
      int idx = it * 256 + tid;
      int n = idx & 15, k = idx >> 4;
      float v = src[k * H_ + n];
      int byteoff = n * 2048 + ((k * 2) ^ ((n & 7) << 4));   // G4 XOR swizzle
      *(h16*)(base + byteoff) = (h16)v;
    }
  }

  // --- init h buffers (broadcast h0 input over batch) ---
  h16* h0b[2] = { hbase,              hbase + B_ * H_ };
  h16* h1b[2] = { hbase + 2*B_*H_,    hbase + 3*B_*H_ };
  for (int it = tid; it < 64 * 16; it += 256) {
    int r = it >> 4, c = it & 15;
    int b = mh * 64 + r, col = j * 16 + c;
    h0b[0][b * H_ + col] = (h16)h0in[col];
    h1b[0][b * H_ + col] = (h16)h0in[H_ + col];
  }
  gridbar(bar, gridDim.x);

  const int rowA = mh * 64 + w * 16 + lm;    // A-fragment row (batch idx)
  const int col  = j * 16 + lm;              // output col
  const int rb   = mh * 64 + w * 16 + kg*4;  // D rows base
  const float bias0 = b0v[col], bias1 = b1v[col];
  const int swx = (lm & 7) << 4;
  const char* L0 = (const char*)wlds + lm * 2048;
  const char* L1 = L0 + 32768;
  const char* L2 = L0 + 65536;

  // xp prefetch: keep next timestep's 4 values in registers; loads issued in
  // phase B of the previous step so HBM latency hides under MFMA work.
  float xpv[4];
#pragma unroll
  for (int r = 0; r < 4; r++) xpv[r] = (float)xp[((rb + r) * T_ + 0) * H_ + col];

  int cur = 0;
  for (int t = 0; t < T_; t++) {
    const int nxt = cur ^ 1;
    // ---------- phase A: h0_new = tanh(Xp[t] + h0 @ Wh0 + b0) ----------
    {
      v4f acc0 = (v4f){0,0,0,0}, acc1 = (v4f){0,0,0,0};
      const v8h* Ap = (const v8h*)h0b[cur] + rowA * 128 + kg;
#pragma unroll
      for (int ks = 0; ks < 32; ks += 2) {
        v8h a0 = Ap[ks * 4], a1 = Ap[ks * 4 + 4];
        v8h f0 = *(const v8h*)(L0 + (((ks    ) * 64 + kg * 16) ^ swx));
        v8h f1 = *(const v8h*)(L0 + (((ks + 1) * 64 + kg * 16) ^ swx));
        acc0 = MFMA16(a0, f0, acc0);
        acc1 = MFMA16(a1, f1, acc1);
      }
      acc0 = acc0 + acc1;
#pragma unroll
      for (int r = 0; r < 4; r++) {
        int b = rb + r;
        float v = fast_tanh(acc0[r] + xpv[r] + bias0);
        h0b[nxt][b * H_ + col] = (h16)v;
        if (t == T_ - 1) out[(size_t)BT_ * H_ + b * 2048 + col] = v;   // h_n layer 0
      }
    }
    gridbar(bar, gridDim.x);
    // ---------- phase B: h1_new = tanh(h0_new @ Wi1 + h1 @ Wh1 + b1) ----------
    {
      // issue next-t xp loads first (independent) so latency hides under MFMAs
      if (t + 1 < T_) {
#pragma unroll
        for (int r = 0; r < 4; r++) xpv[r] = (float)xp[((rb + r) * T_ + (t + 1)) * H_ + col];
      }
      v4f acc0 = (v4f){0,0,0,0}, acc1 = (v4f){0,0,0,0};
      const v8h* Ap0 = (const v8h*)h0b[nxt] + rowA * 128 + kg;
      const v8h* Ap1 = (const v8h*)h1b[cur] + rowA * 128 + kg;
#pragma unroll
      for (int ks = 0; ks < 32; ks += 2) {
        v8h a0 = Ap0[ks * 4], a1 = Ap0[ks * 4 + 4];
        v8h f0 = *(const v8h*)(L1 + (((ks    ) * 64 + kg * 16) ^ swx));
        v8h f1 = *(const v8h*)(L1 + (((ks + 1) * 64 + kg * 16) ^ swx));
        acc0 = MFMA16(a0, f0, acc0);
        acc1 = MFMA16(a1, f1, acc1);
      }
#pragma unroll
      for (int ks = 0; ks < 32; ks += 2) {
        v8h a0 = Ap1[ks * 4], a1 = Ap1[ks * 4 + 4];
        v8h f0 = *(const v8h*)(L2 + (((ks    ) * 64 + kg * 16) ^ swx));
        v8h f1 = *(const v8h*)(L2 + (((ks + 1) * 64 + kg * 16) ^ swx));
        acc0 = MFMA16(a0, f0, acc0);
        acc1 = MFMA16(a1, f1, acc1);
      }
      acc0 = acc0 + acc1;
#pragma unroll
      for (int r = 0; r < 4; r++) {
        int b = rb + r;
        float v = fast_tanh(acc0[r] + bias1);
        h1b[nxt][b * H_ + col] = (h16)v;
        out[(b * T_ + t) * H_ + col] = v;                               // output[b][t][:]
        if (t == T_ - 1) out[(size_t)BT_ * H_ + b * 2048 + H_ + col] = v; // h_n layer 1
      }
    }
    gridbar(bar, gridDim.x);
    cur = nxt;
  }
}

extern "C" void kernel_launch(void* const* d_in, const int* in_sizes, int n_in,
                              void* d_out, int out_size, void* d_ws, size_t ws_size,
                              hipStream_t stream) {
  const float* x  = (const float*)d_in[0];
  const float* h0 = (const float*)d_in[1];
  const float* wi = (const float*)d_in[2];
  const float* bi = (const float*)d_in[3];
  const float* wh = (const float*)d_in[4];
  const float* bh = (const float*)d_in[5];
  float* out = (float*)d_out;
  char* ws = (char*)d_ws;

  hipMemsetAsync(ws + OFF_BAR, 0, 256, stream);   // barrier state

  k_prep_x   <<<BT_ * H_ / 8 / 256, 256, 0, stream>>>(x, (h16*)(ws + OFF_XH));
  k_prep_bias<<<8,   256, 0, stream>>>(bi, bh, (float*)(ws + OFF_B0), (float*)(ws + OFF_B1));
  k_prep_wt  <<<256, 256, 0, stream>>>(wi, (h16*)(ws + OFF_WI0T));
  k_xp_gemm  <<<4096, 256, 0, stream>>>((const h16*)(ws + OFF_XH),
                                        (const h16*)(ws + OFF_WI0T),
                                        (h16*)(ws + OFF_XP));
  k_scan     <<<128, 256, 0, stream>>>(wi, wh, h0,
                                       (const h16*)(ws + OFF_XP),
                                       (const float*)(ws + OFF_B0),
                                       (const float*)(ws + OFF_B1),
                                       (h16*)(ws + OFF_H0B0),
                                       out,
                                       (unsigned*)(ws + OFF_BAR));
}

// Round 4
// 5168.435 us; speedup vs baseline: 1.5442x; 1.5442x over previous
//
#include <hip/hip_runtime.h>

#define B_ 128
#define T_ 256
#define H_ 1024
#define BT_ (B_*T_)

typedef _Float16 h16;
typedef _Float16 v8h __attribute__((ext_vector_type(8)));
typedef float v4f __attribute__((ext_vector_type(4)));

// ---- workspace layout (bytes) ----
#define OFF_BAR   0u                                  // 128 flags, one per 64B line
#define OFF_REL   8192u                               // release word
#define OFF_B0    12288u
#define OFF_B1    16384u
#define OFF_H     20480u                              // 4 x 256KB: h0[0],h0[1],h1[0],h1[1]
#define OFF_WI0T  (OFF_H + 4u*262144u)                // each WT: H*H fp16 = 2MB
#define OFF_WH0T  (OFF_WI0T + 2097152u)
#define OFF_WI1T  (OFF_WH0T + 2097152u)
#define OFF_WH1T  (OFF_WI1T + 2097152u)
#define OFF_XH    (OFF_WH1T + 2097152u)               // BT*H fp16 = 64MB
#define OFF_XP    (OFF_XH + (size_t)BT_*H_*2u)        // BT*H fp16 = 64MB, layout [T][B][H]

#define MFMA16(a,b,c) __builtin_amdgcn_mfma_f32_16x16x32_f16((a),(b),(c),0,0,0)

__device__ __forceinline__ float fast_tanh(float x) {
  float e = __expf(2.0f * x);
  return 1.0f - __fdividef(2.0f, e + 1.0f);
}

// flag barrier: wg stores monotonic sense to its own cacheline; master (wg 0)
// polls all flags with one wave, then writes release word; others poll release.
__device__ __forceinline__ void flagbar(unsigned* flags, unsigned* rel, int wgid, unsigned sense) {
  __syncthreads();                       // drains vmcnt: all wg stores are in L2
  if (threadIdx.x < 64) {
    if (threadIdx.x == 0) {
      __threadfence();                   // release: writeback L2 to coherence point
      __hip_atomic_store(&flags[wgid * 16], sense, __ATOMIC_RELAXED, __HIP_MEMORY_SCOPE_AGENT);
    }
    if (wgid == 0) {
      const int l = threadIdx.x;
      for (;;) {
        unsigned a = __hip_atomic_load(&flags[l * 16],        __ATOMIC_RELAXED, __HIP_MEMORY_SCOPE_AGENT);
        unsigned b = __hip_atomic_load(&flags[(l + 64) * 16], __ATOMIC_RELAXED, __HIP_MEMORY_SCOPE_AGENT);
        if (__all(a >= sense && b >= sense)) break;
        __builtin_amdgcn_s_sleep(1);
      }
      if (threadIdx.x == 0)
        __hip_atomic_store(rel, sense, __ATOMIC_RELAXED, __HIP_MEMORY_SCOPE_AGENT);
    } else if (threadIdx.x == 0) {
      while (__hip_atomic_load(rel, __ATOMIC_RELAXED, __HIP_MEMORY_SCOPE_AGENT) < sense)
        __builtin_amdgcn_s_sleep(2);
    }
    __threadfence();                     // acquire: invalidate L1/L2 before reading peer state
  }
  __syncthreads();
}

// ---- prep: x (f32) -> fp16 ----
__global__ void k_prep_x(const float* __restrict__ x, h16* __restrict__ xh) {
  int i = blockIdx.x * 256 + threadIdx.x;
  const float4* xin = (const float4*)x;
  float4 f0 = xin[i * 2], f1 = xin[i * 2 + 1];
  v8h o;
  o[0]=(h16)f0.x; o[1]=(h16)f0.y; o[2]=(h16)f0.z; o[3]=(h16)f0.w;
  o[4]=(h16)f1.x; o[5]=(h16)f1.y; o[6]=(h16)f1.z; o[7]=(h16)f1.w;
  ((v8h*)xh)[i] = o;
}

// ---- prep: fused biases ----
__global__ void k_prep_bias(const float* __restrict__ bi, const float* __restrict__ bh,
                            float* __restrict__ b0, float* __restrict__ b1) {
  int i = blockIdx.x * 256 + threadIdx.x;
  float v = bi[i] + bh[i];
  if (i < H_) b0[i] = v; else b1[i - H_] = v;
}

// ---- prep: WT[n][k] = (fp16) W[k][n] ----
__global__ void k_prep_wt(const float* __restrict__ W, h16* __restrict__ WT) {
  __shared__ float tile[64][65];
  int bx = blockIdx.x & 15, by = blockIdx.x >> 4;
  int tid = threadIdx.x;
  int c = tid & 63, r4 = tid >> 6;
#pragma unroll
  for (int i = 0; i < 16; i++) { int r = i * 4 + r4; tile[r][c] = W[(by*64 + r)*H_ + bx*64 + c]; }
  __syncthreads();
#pragma unroll
  for (int i = 0; i < 16; i++) { int rr = i * 4 + r4; WT[(bx*64 + rr)*H_ + by*64 + c] = (h16)tile[c][rr]; }
}

// ---- Xp = xh @ Wi0 -> fp16, stored [T][B][H] ----
__global__ __launch_bounds__(256) void k_xp_gemm(const h16* __restrict__ xh,
                                                 const h16* __restrict__ wt,
                                                 h16* __restrict__ xp) {
  int w = threadIdx.x >> 6, l = threadIdx.x & 63;
  int lm = l & 15, kg = l >> 4;
  int wgM = blockIdx.x & 255, wgN = blockIdx.x >> 8;
  int mbase = wgM * 128 + w * 32;
  int nbase = wgN * 64;

  v4f acc[2][4];
#pragma unroll
  for (int a = 0; a < 2; a++)
#pragma unroll
    for (int b = 0; b < 4; b++) acc[a][b] = (v4f){0.f,0.f,0.f,0.f};

  const v8h* A0 = (const v8h*)xh + (mbase + lm) * 128 + kg;
  const v8h* A1 = A0 + 16 * 128;
  const v8h* Bp0 = (const v8h*)wt + (nbase +  0 + lm) * 128 + kg;
  const v8h* Bp1 = (const v8h*)wt + (nbase + 16 + lm) * 128 + kg;
  const v8h* Bp2 = (const v8h*)wt + (nbase + 32 + lm) * 128 + kg;
  const v8h* Bp3 = (const v8h*)wt + (nbase + 48 + lm) * 128 + kg;

#pragma unroll 4
  for (int ks = 0; ks < 32; ks++) {
    v8h a0 = A0[ks * 4], a1 = A1[ks * 4];
    v8h b0 = Bp0[ks * 4], b1 = Bp1[ks * 4], b2 = Bp2[ks * 4], b3 = Bp3[ks * 4];
    acc[0][0] = MFMA16(a0, b0, acc[0][0]);  acc[1][0] = MFMA16(a1, b0, acc[1][0]);
    acc[0][1] = MFMA16(a0, b1, acc[0][1]);  acc[1][1] = MFMA16(a1, b1, acc[1][1]);
    acc[0][2] = MFMA16(a0, b2, acc[0][2]);  acc[1][2] = MFMA16(a1, b2, acc[1][2]);
    acc[0][3] = MFMA16(a0, b3, acc[0][3]);  acc[1][3] = MFMA16(a1, b3, acc[1][3]);
  }
#pragma unroll
  for (int mi = 0; mi < 2; mi++)
#pragma unroll
    for (int ni = 0; ni < 4; ni++)
#pragma unroll
      for (int r = 0; r < 4; r++) {
        int row = mbase + mi * 16 + kg * 4 + r;      // bt index
        int b = row >> 8, t = row & 255;             // T = 256
        int col = nbase + ni * 16 + lm;
        xp[((t * B_) + b) * H_ + col] = (h16)acc[mi][ni][r];
      }
}

// ---- persistent pipelined scan ----
// 128 wgs: pool A (wg 0..63) layer 0, pool B (wg 64..127) layer 1 (one step behind).
// Per pool: 2 batch-halves x 32 col-blocks (32 cols). Waves k-split K=1024 into 4x256;
// weight fragments live in VGPRs; cross-wave reduce via 32KB LDS.
__global__ __launch_bounds__(256, 1) void k_scan(const h16* __restrict__ wh0t,
                                                 const h16* __restrict__ wi1t,
                                                 const h16* __restrict__ wh1t,
                                                 const float* __restrict__ h0in,
                                                 const h16* __restrict__ xp,
                                                 const float* __restrict__ b0v,
                                                 const float* __restrict__ b1v,
                                                 h16* __restrict__ hbase,
                                                 float* __restrict__ out,
                                                 unsigned* __restrict__ flags,
                                                 unsigned* __restrict__ rel) {
  __shared__ v4f red[2048];   // 16 slots x 128 v4f = 32 KB
  const int tid = threadIdx.x;
  const int wgid = blockIdx.x;
  const int pool = wgid >> 6;
  const int p = wgid & 63;
  const int mh = p >> 5, j = p & 31;
  const int rbase = mh * 64, cbase = j * 32;
  const int w = tid >> 6, l = tid & 63, lm = l & 15, kg = l >> 4;
  const int kvb = w * 32;                    // this wave's v8h k-base (k = w*256)

  h16* h0b[2] = { hbase,           hbase + 131072 };
  h16* h1b[2] = { hbase + 262144,  hbase + 393216 };

  // --- one-time: weight fragments -> registers ---
  v8h wa[2][8], wb[2][8];
  {
    const v8h* WA = (const v8h*)((pool == 0) ? wh0t : wi1t);
    const v8h* WB = (const v8h*)wh1t;
#pragma unroll
    for (int n = 0; n < 2; n++)
#pragma unroll
      for (int ks = 0; ks < 8; ks++) {
        int nidx = (cbase + 16 * n + lm) * 128 + kvb + ks * 4 + kg;
        wa[n][ks] = WA[nidx];
        wb[n][ks] = WB[nidx];               // unused by pool A (harmless extra load)
      }
  }

  // --- init h state, parity 1 ---
  {
    h16* dst = (pool == 0) ? h0b[1] : h1b[1];
    const float* src = h0in + pool * H_;
#pragma unroll
    for (int i = 0; i < 8; i++) {
      int e = tid * 8 + i;
      int r = e >> 5, c = e & 31;
      dst[(rbase + r) * H_ + cbase + c] = (h16)src[cbase + c];
    }
  }
  unsigned sense = 1;
  flagbar(flags, rel, wgid, sense); sense++;

  const float bs0 = (pool == 0) ? b0v[cbase + lm]      : b1v[cbase + lm];
  const float bs1 = (pool == 0) ? b0v[cbase + 16 + lm] : b1v[cbase + 16 + lm];

  for (int k = 0; k <= T_; ++k) {
    if (pool == 0 && k < T_) {
      // ---- layer 0, t = k ----
      float xq[8];
#pragma unroll
      for (int n = 0; n < 2; n++)
#pragma unroll
        for (int r = 0; r < 4; r++)
          xq[n * 4 + r] = (float)xp[((k * B_) + rbase + 16 * w + kg * 4 + r) * H_ + cbase + 16 * n + lm];

      const v8h* S = (const v8h*)h0b[(k + 1) & 1];    // h0[k-1]
      v4f acc[4][2];
#pragma unroll
      for (int m = 0; m < 4; m++) { acc[m][0] = (v4f){0,0,0,0}; acc[m][1] = (v4f){0,0,0,0}; }
#pragma unroll
      for (int m = 0; m < 4; m++)
#pragma unroll
        for (int ks = 0; ks < 8; ks++) {
          v8h a = S[(rbase + 16 * m + lm) * 128 + kvb + ks * 4 + kg];
          acc[m][0] = MFMA16(a, wa[0][ks], acc[m][0]);
          acc[m][1] = MFMA16(a, wa[1][ks], acc[m][1]);
        }
      // cross-wave k-reduce
#pragma unroll
      for (int m = 0; m < 4; m++)
        if (m != w) {
          red[(m * 4 + w) * 128 +      l] = acc[m][0];
          red[(m * 4 + w) * 128 + 64 + l] = acc[m][1];
        }
      __syncthreads();
      v4f own0 = acc[0][0], own1 = acc[0][1];
      if (w == 1) { own0 = acc[1][0]; own1 = acc[1][1]; }
      else if (w == 2) { own0 = acc[2][0]; own1 = acc[2][1]; }
      else if (w == 3) { own0 = acc[3][0]; own1 = acc[3][1]; }
#pragma unroll
      for (int sw = 0; sw < 4; sw++)
        if (sw != w) {
          own0 += red[(w * 4 + sw) * 128 +      l];
          own1 += red[(w * 4 + sw) * 128 + 64 + l];
        }
      h16* D = h0b[k & 1];
#pragma unroll
      for (int n = 0; n < 2; n++)
#pragma unroll
        for (int r = 0; r < 4; r++) {
          float v = fast_tanh((n ? own1[r] : own0[r]) + xq[n * 4 + r] + (n ? bs1 : bs0));
          int row = rbase + 16 * w + kg * 4 + r, col = cbase + 16 * n + lm;
          D[row * H_ + col] = (h16)v;
          if (k == T_ - 1) out[(size_t)BT_ * H_ + row * 2048 + col] = v;   // h_n layer 0
        }
    } else if (pool == 1 && k >= 1) {
      // ---- layer 1, t = k-1 ----
      const v8h* S0 = (const v8h*)h0b[(k + 1) & 1];   // h0[k-1]
      const v8h* S1 = (const v8h*)h1b[k & 1];         // h1[k-2]
      v4f acc[4][2];
#pragma unroll
      for (int m = 0; m < 4; m++) { acc[m][0] = (v4f){0,0,0,0}; acc[m][1] = (v4f){0,0,0,0}; }
#pragma unroll
      for (int m = 0; m < 4; m++)
#pragma unroll
        for (int ks = 0; ks < 8; ks++) {
          v8h a = S0[(rbase + 16 * m + lm) * 128 + kvb + ks * 4 + kg];
          acc[m][0] = MFMA16(a, wa[0][ks], acc[m][0]);
          acc[m][1] = MFMA16(a, wa[1][ks], acc[m][1]);
        }
#pragma unroll
      for (int m = 0; m < 4; m++)
#pragma unroll
        for (int ks = 0; ks < 8; ks++) {
          v8h a = S1[(rbase + 16 * m + lm) * 128 + kvb + ks * 4 + kg];
          acc[m][0] = MFMA16(a, wb[0][ks], acc[m][0]);
          acc[m][1] = MFMA16(a, wb[1][ks], acc[m][1]);
        }
#pragma unroll
      for (int m = 0; m < 4; m++)
        if (m != w) {
          red[(m * 4 + w) * 128 +      l] = acc[m][0];
          red[(m * 4 + w) * 128 + 64 + l] = acc[m][1];
        }
      __syncthreads();
      v4f own0 = acc[0][0], own1 = acc[0][1];
      if (w == 1) { own0 = acc[1][0]; own1 = acc[1][1]; }
      else if (w == 2) { own0 = acc[2][0]; own1 = acc[2][1]; }
      else if (w == 3) { own0 = acc[3][0]; own1 = acc[3][1]; }
#pragma unroll
      for (int sw = 0; sw < 4; sw++)
        if (sw != w) {
          own0 += red[(w * 4 + sw) * 128 +      l];
          own1 += red[(w * 4 + sw) * 128 + 64 + l];
        }
      const int t = k - 1;
      h16* D = h1b[(k + 1) & 1];
#pragma unroll
      for (int n = 0; n < 2; n++)
#pragma unroll
        for (int r = 0; r < 4; r++) {
          float v = fast_tanh((n ? own1[r] : own0[r]) + (n ? bs1 : bs0));
          int row = rbase + 16 * w + kg * 4 + r, col = cbase + 16 * n + lm;
          D[row * H_ + col] = (h16)v;
          out[((size_t)row * T_ + t) * H_ + col] = v;                      // output[b][t][:]
          if (t == T_ - 1) out[(size_t)BT_ * H_ + row * 2048 + 1024 + col] = v;  // h_n layer 1
        }
    }
    if (k < T_) { flagbar(flags, rel, wgid, sense); sense++; }
  }
}

extern "C" void kernel_launch(void* const* d_in, const int* in_sizes, int n_in,
                              void* d_out, int out_size, void* d_ws, size_t ws_size,
                              hipStream_t stream) {
  const float* x  = (const float*)d_in[0];
  const float* h0 = (const float*)d_in[1];
  const float* wi = (const float*)d_in[2];
  const float* bi = (const float*)d_in[3];
  const float* wh = (const float*)d_in[4];
  const float* bh = (const float*)d_in[5];
  float* out = (float*)d_out;
  char* ws = (char*)d_ws;

  hipMemsetAsync(ws + OFF_BAR, 0, 8448, stream);   // flags + release

  k_prep_x   <<<BT_ * H_ / 8 / 256, 256, 0, stream>>>(x, (h16*)(ws + OFF_XH));
  k_prep_bias<<<8,   256, 0, stream>>>(bi, bh, (float*)(ws + OFF_B0), (float*)(ws + OFF_B1));
  k_prep_wt  <<<256, 256, 0, stream>>>(wi,            (h16*)(ws + OFF_WI0T));
  k_prep_wt  <<<256, 256, 0, stream>>>(wh,            (h16*)(ws + OFF_WH0T));
  k_prep_wt  <<<256, 256, 0, stream>>>(wi + H_ * H_,  (h16*)(ws + OFF_WI1T));
  k_prep_wt  <<<256, 256, 0, stream>>>(wh + H_ * H_,  (h16*)(ws + OFF_WH1T));
  k_xp_gemm  <<<4096, 256, 0, stream>>>((const h16*)(ws + OFF_XH),
                                        (const h16*)(ws + OFF_WI0T),
                                        (h16*)(ws + OFF_XP));
  k_scan     <<<128, 256, 0, stream>>>((const h16*)(ws + OFF_WH0T),
                                       (const h16*)(ws + OFF_WI1T),
                                       (const h16*)(ws + OFF_WH1T),
                                       h0,
                                       (const h16*)(ws + OFF_XP),
                                       (const float*)(ws + OFF_B0),
                                       (const float*)(ws + OFF_B1),
                                       (h16*)(ws + OFF_H),
                                       out,
                                       (unsigned*)(ws + OFF_BAR),
                                       (unsigned*)(ws + OFF_REL));
}

// Round 5
// 2043.702 us; speedup vs baseline: 3.9052x; 2.5290x over previous
//
#include <hip/hip_runtime.h>

#define B_ 128
#define T_ 256
#define H_ 1024
#define BT_ (B_*T_)
#define NG 8          // batch groups
#define GR 16         // rows per group

typedef _Float16 h16;
typedef _Float16 v8h __attribute__((ext_vector_type(8)));
typedef float v4f __attribute__((ext_vector_type(4)));

// ---- workspace layout (bytes) ----
#define OFF_AFL   0u                                  // [NG][16] flags, 64B spacing
#define OFF_BFL   8192u
#define OFF_B0    16384u
#define OFF_B1    20480u
#define OFF_H0S   24576u                              // [4][NG][GR][H] h16 = 1MB
#define OFF_H1S   (OFF_H0S + 1048576u)                // [2][NG][GR][H] h16 = 512KB
#define OFF_WI0T  (OFF_H1S + 524288u)                 // each WT: 2MB fp16
#define OFF_WH0T  (OFF_WI0T + 2097152u)
#define OFF_WI1T  (OFF_WH0T + 2097152u)
#define OFF_WH1T  (OFF_WI1T + 2097152u)
#define OFF_XH    (OFF_WH1T + 2097152u)               // 64MB
#define OFF_XP    (OFF_XH + (size_t)BT_*H_*2u)        // 64MB, [T][B][H]

#define MFMA16(a,b,c) __builtin_amdgcn_mfma_f32_16x16x32_f16((a),(b),(c),0,0,0)

__device__ __forceinline__ float fast_tanh(float x) {
  float e = __expf(2.0f * x);
  return 1.0f - __fdividef(2.0f, e + 1.0f);
}

__device__ __forceinline__ void cstore8(h16* p, unsigned long long v) {
  __hip_atomic_store((unsigned long long*)p, v, __ATOMIC_RELAXED, __HIP_MEMORY_SCOPE_AGENT);
}
__device__ __forceinline__ unsigned long long cload8(const h16* p) {
  return __hip_atomic_load((const unsigned long long*)p, __ATOMIC_RELAXED, __HIP_MEMORY_SCOPE_AGENT);
}

// wave 0 polls 32 per-group flags (one per lane-pair set); bounded spin.
__device__ __forceinline__ void wait_flags(const unsigned* A, const unsigned* B,
                                           unsigned ta, unsigned tb, int l) {
  int li = l & 31;
  const unsigned* p = (li < 16) ? (A + li * 16) : (B + (li - 16) * 16);
  unsigned th = (li < 16) ? ta : tb;
  for (int it = 0; it < (1 << 14); ++it) {
    unsigned f = __hip_atomic_load(p, __ATOMIC_RELAXED, __HIP_MEMORY_SCOPE_AGENT);
    if (__all(f >= th)) break;
    __builtin_amdgcn_s_sleep(1);
  }
}

// ---- prep: x (f32) -> fp16 ----
__global__ void k_prep_x(const float* __restrict__ x, h16* __restrict__ xh) {
  int i = blockIdx.x * 256 + threadIdx.x;
  const float4* xin = (const float4*)x;
  float4 f0 = xin[i * 2], f1 = xin[i * 2 + 1];
  v8h o;
  o[0]=(h16)f0.x; o[1]=(h16)f0.y; o[2]=(h16)f0.z; o[3]=(h16)f0.w;
  o[4]=(h16)f1.x; o[5]=(h16)f1.y; o[6]=(h16)f1.z; o[7]=(h16)f1.w;
  ((v8h*)xh)[i] = o;
}

__global__ void k_prep_bias(const float* __restrict__ bi, const float* __restrict__ bh,
                            float* __restrict__ b0, float* __restrict__ b1) {
  int i = blockIdx.x * 256 + threadIdx.x;
  float v = bi[i] + bh[i];
  if (i < H_) b0[i] = v; else b1[i - H_] = v;
}

// ---- prep: WT[n][k] = (fp16) W[k][n] ----
__global__ void k_prep_wt(const float* __restrict__ W, h16* __restrict__ WT) {
  __shared__ float tile[64][65];
  int bx = blockIdx.x & 15, by = blockIdx.x >> 4;
  int tid = threadIdx.x;
  int c = tid & 63, r4 = tid >> 6;
#pragma unroll
  for (int i = 0; i < 16; i++) { int r = i * 4 + r4; tile[r][c] = W[(by*64 + r)*H_ + bx*64 + c]; }
  __syncthreads();
#pragma unroll
  for (int i = 0; i < 16; i++) { int rr = i * 4 + r4; WT[(bx*64 + rr)*H_ + by*64 + c] = (h16)tile[c][rr]; }
}

// ---- Xp = xh @ Wi0 -> fp16, stored [T][B][H] ----
__global__ __launch_bounds__(256) void k_xp_gemm(const h16* __restrict__ xh,
                                                 const h16* __restrict__ wt,
                                                 h16* __restrict__ xp) {
  int w = threadIdx.x >> 6, l = threadIdx.x & 63;
  int lm = l & 15, kg = l >> 4;
  int wgM = blockIdx.x & 255, wgN = blockIdx.x >> 8;
  int mbase = wgM * 128 + w * 32;
  int nbase = wgN * 64;

  v4f acc[2][4];
#pragma unroll
  for (int a = 0; a < 2; a++)
#pragma unroll
    for (int b = 0; b < 4; b++) acc[a][b] = (v4f){0.f,0.f,0.f,0.f};

  const v8h* A0 = (const v8h*)xh + (mbase + lm) * 128 + kg;
  const v8h* A1 = A0 + 16 * 128;
  const v8h* Bp0 = (const v8h*)wt + (nbase +  0 + lm) * 128 + kg;
  const v8h* Bp1 = (const v8h*)wt + (nbase + 16 + lm) * 128 + kg;
  const v8h* Bp2 = (const v8h*)wt + (nbase + 32 + lm) * 128 + kg;
  const v8h* Bp3 = (const v8h*)wt + (nbase + 48 + lm) * 128 + kg;

#pragma unroll 4
  for (int ks = 0; ks < 32; ks++) {
    v8h a0 = A0[ks * 4], a1 = A1[ks * 4];
    v8h b0 = Bp0[ks * 4], b1 = Bp1[ks * 4], b2 = Bp2[ks * 4], b3 = Bp3[ks * 4];
    acc[0][0] = MFMA16(a0, b0, acc[0][0]);  acc[1][0] = MFMA16(a1, b0, acc[1][0]);
    acc[0][1] = MFMA16(a0, b1, acc[0][1]);  acc[1][1] = MFMA16(a1, b1, acc[1][1]);
    acc[0][2] = MFMA16(a0, b2, acc[0][2]);  acc[1][2] = MFMA16(a1, b2, acc[1][2]);
    acc[0][3] = MFMA16(a0, b3, acc[0][3]);  acc[1][3] = MFMA16(a1, b3, acc[1][3]);
  }
#pragma unroll
  for (int mi = 0; mi < 2; mi++)
#pragma unroll
    for (int ni = 0; ni < 4; ni++)
#pragma unroll
      for (int r = 0; r < 4; r++) {
        int row = mbase + mi * 16 + kg * 4 + r;   // bt index
        int b = row >> 8, t = row & 255;
        int col = nbase + ni * 16 + lm;
        xp[((t * B_) + b) * H_ + col] = (h16)acc[mi][ni][r];
      }
}

// ---- persistent scan: 8 independent groups x (16 layer-0 wgs + 16 layer-1 wgs) ----
// Group g owns batch rows [16g,16g+16). Layer-1 pipelined one tick behind layer-0.
// h0 ring 4-deep, h1 2-deep; state moves via agent-scope 8B atomics (IF-coherent).
__global__ __launch_bounds__(256, 1) void k_scan(const h16* __restrict__ wh0t,
                                                 const h16* __restrict__ wi1t,
                                                 const h16* __restrict__ wh1t,
                                                 const float* __restrict__ h0in,
                                                 const h16* __restrict__ xp,
                                                 const float* __restrict__ b0v,
                                                 const float* __restrict__ b1v,
                                                 h16* __restrict__ h0s,
                                                 h16* __restrict__ h1s,
                                                 float* __restrict__ out,
                                                 unsigned* __restrict__ afl,
                                                 unsigned* __restrict__ bfl) {
  __shared__ v4f red[4][4][64];      // [n][srcwave][lane] 16KB k-reduce
  __shared__ float trf[4][16][20];   // per-wave 16x16 transpose (+pad)

  const int tid = threadIdx.x;
  const int wv = tid >> 6, l = tid & 63, lm = l & 15, kg = l >> 4;
  const int gid = blockIdx.x >> 5;
  const int sub = blockIdx.x & 31;
  const int isB = sub >> 4;                // 0: layer 0, 1: layer 1
  const int cw = sub & 15;
  const int cbase = cw * 64;
  const int gbase = gid * GR;
  const int c0 = cbase + 16 * wv;          // this wave's owned 16 cols
  unsigned* myAfl = afl + gid * 256;       // 16 flags x 16 uints (64B lines)
  unsigned* myBfl = bfl + gid * 256;

  // --- weights (read-only, normal cached loads) -> registers ---
  v8h wa[4][8], wb[4][8];
  {
    const v8h* WA = (const v8h*)(isB ? wi1t : wh0t);
    const v8h* WB = (const v8h*)wh1t;
#pragma unroll
    for (int n = 0; n < 4; n++)
#pragma unroll
      for (int ks = 0; ks < 8; ks++) {
        int nidx = (cbase + 16 * n + lm) * 128 + wv * 32 + ks * 4 + kg;
        wa[n][ks] = WA[nidx];
        wb[n][ks] = isB ? WB[nidx] : wa[n][ks];
      }
  }

  // --- init state (broadcast h0in over batch rows): A -> h0 slot 3, B -> h1 slot 1 ---
  {
    int row = tid & 15, cs = cbase + (tid >> 4) * 4;
    const float* src = h0in + (isB ? H_ : 0);
    union { unsigned long long u; h16 h[4]; } pk;
    pk.h[0] = (h16)src[cs];     pk.h[1] = (h16)src[cs + 1];
    pk.h[2] = (h16)src[cs + 2]; pk.h[3] = (h16)src[cs + 3];
    h16* dst = isB ? (h1s + ((size_t)(1 * NG + gid) * GR + row) * H_ + cs)
                   : (h0s + ((size_t)(3 * NG + gid) * GR + row) * H_ + cs);
    cstore8(dst, pk.u);
  }
  __syncthreads();
  if (tid == 0)
    __hip_atomic_store((isB ? myBfl : myAfl) + cw * 16, 1u,
                       __ATOMIC_RELAXED, __HIP_MEMORY_SCOPE_AGENT);

  const float bias = (isB ? b1v : b0v)[c0 + lm];

  for (int k = 0; k < T_; ++k) {
    // ---- prefetch xq (layer 0 only; independent of flags) ----
    float xq0 = 0.f, xq1 = 0.f, xq2 = 0.f, xq3 = 0.f;
    if (!isB) {
      const h16* xb = xp + (size_t)(k * B_ + gbase + kg * 4) * H_ + c0 + lm;
      xq0 = (float)xb[0]; xq1 = (float)xb[H_]; xq2 = (float)xb[2 * H_]; xq3 = (float)xb[3 * H_];
    }
    // ---- wait for dependencies ----
    unsigned thA, thB;
    if (!isB) { thA = (unsigned)(k + 1); thB = (k >= 4) ? (unsigned)(k - 2) : 0u; }
    else      { thA = (unsigned)(k + 2); thB = (unsigned)(k + 1); }
    if (wv == 0) wait_flags(myAfl, myBfl, thA, thB, l);
    __syncthreads();
    asm volatile("" ::: "memory");

    // ---- load state fragments (agent-coherent 8B loads) ----
    const int s0slot = isB ? (k & 3) : ((k + 3) & 3);   // B reads h0[k]; A reads h0[k-1]
    v8h s0f[8], s1f[8];
    {
      const h16* sb = h0s + ((size_t)(s0slot * NG + gid) * GR + lm) * H_ + wv * 256 + kg * 8;
#pragma unroll
      for (int ks = 0; ks < 8; ks++) {
        union { unsigned long long u[2]; v8h v; } u;
        u.u[0] = cload8(sb + ks * 32);
        u.u[1] = cload8(sb + ks * 32 + 4);
        s0f[ks] = u.v;
      }
    }
    if (isB) {
      const int s1slot = (k + 1) & 1;                   // h1[k-1]
      const h16* sb = h1s + ((size_t)(s1slot * NG + gid) * GR + lm) * H_ + wv * 256 + kg * 8;
#pragma unroll
      for (int ks = 0; ks < 8; ks++) {
        union { unsigned long long u[2]; v8h v; } u;
        u.u[0] = cload8(sb + ks * 32);
        u.u[1] = cload8(sb + ks * 32 + 4);
        s1f[ks] = u.v;
      }
    }

    // ---- MFMA: partials for all 4 n-tiles over this wave's k-slice ----
    v4f acc[4];
#pragma unroll
    for (int n = 0; n < 4; n++) acc[n] = (v4f){0.f, 0.f, 0.f, 0.f};
#pragma unroll
    for (int n = 0; n < 4; n++)
#pragma unroll
      for (int ks = 0; ks < 8; ks++) acc[n] = MFMA16(s0f[ks], wa[n][ks], acc[n]);
    if (isB) {
#pragma unroll
      for (int n = 0; n < 4; n++)
#pragma unroll
        for (int ks = 0; ks < 8; ks++) acc[n] = MFMA16(s1f[ks], wb[n][ks], acc[n]);
    }

    // ---- cross-wave k-reduce: wave w owns n-tile w ----
#pragma unroll
    for (int n = 0; n < 4; n++) if (n != wv) red[n][wv][l] = acc[n];
    __syncthreads();
    v4f own = acc[0];
    if (wv == 1) own = acc[1]; else if (wv == 2) own = acc[2]; else if (wv == 3) own = acc[3];
#pragma unroll
    for (int sw = 0; sw < 4; sw++) if (sw != wv) own += red[wv][sw][l];

    // ---- bias(+xp) + tanh, then transpose 16x16 tile via LDS (wave-local) ----
    {
      float v0 = fast_tanh(own[0] + bias + xq0);
      float v1 = fast_tanh(own[1] + bias + xq1);
      float v2 = fast_tanh(own[2] + bias + xq2);
      float v3 = fast_tanh(own[3] + bias + xq3);
      trf[wv][kg * 4 + 0][lm] = v0;
      trf[wv][kg * 4 + 1][lm] = v1;
      trf[wv][kg * 4 + 2][lm] = v2;
      trf[wv][kg * 4 + 3][lm] = v3;
    }
    float o0 = trf[wv][lm][kg * 4 + 0];
    float o1 = trf[wv][lm][kg * 4 + 1];
    float o2 = trf[wv][lm][kg * 4 + 2];
    float o3 = trf[wv][lm][kg * 4 + 3];

    union { unsigned long long u; h16 h[4]; } pk;
    pk.h[0] = (h16)o0; pk.h[1] = (h16)o1; pk.h[2] = (h16)o2; pk.h[3] = (h16)o3;
    if (!isB) {
      h16* hdst = h0s + ((size_t)((k & 3) * NG + gid) * GR + lm) * H_ + c0 + kg * 4;
      cstore8(hdst, pk.u);
      if (k == T_ - 1) {
        float4 f4 = {o0, o1, o2, o3};
        *(float4*)(out + (size_t)BT_ * H_ + (size_t)(gbase + lm) * 2048 + c0 + kg * 4) = f4;
      }
    } else {
      h16* hdst = h1s + ((size_t)((k & 1) * NG + gid) * GR + lm) * H_ + c0 + kg * 4;
      cstore8(hdst, pk.u);
      float4 f4 = {o0, o1, o2, o3};
      *(float4*)(out + ((size_t)(gbase + lm) * T_ + k) * H_ + c0 + kg * 4) = f4;
      if (k == T_ - 1)
        *(float4*)(out + (size_t)BT_ * H_ + (size_t)(gbase + lm) * 2048 + 1024 + c0 + kg * 4) = f4;
    }

    // ---- arrive: drain stores (syncthreads emits vmcnt(0)), then flag ----
    __syncthreads();
    if (tid == 0)
      __hip_atomic_store((isB ? myBfl : myAfl) + cw * 16, (unsigned)(k + 2),
                         __ATOMIC_RELAXED, __HIP_MEMORY_SCOPE_AGENT);
  }
}

extern "C" void kernel_launch(void* const* d_in, const int* in_sizes, int n_in,
                              void* d_out, int out_size, void* d_ws, size_t ws_size,
                              hipStream_t stream) {
  const float* x  = (const float*)d_in[0];
  const float* h0 = (const float*)d_in[1];
  const float* wi = (const float*)d_in[2];
  const float* bi = (const float*)d_in[3];
  const float* wh = (const float*)d_in[4];
  const float* bh = (const float*)d_in[5];
  float* out = (float*)d_out;
  char* ws = (char*)d_ws;

  hipMemsetAsync(ws + OFF_AFL, 0, 16384, stream);   // flags

  k_prep_x   <<<BT_ * H_ / 8 / 256, 256, 0, stream>>>(x, (h16*)(ws + OFF_XH));
  k_prep_bias<<<8,   256, 0, stream>>>(bi, bh, (float*)(ws + OFF_B0), (float*)(ws + OFF_B1));
  k_prep_wt  <<<256, 256, 0, stream>>>(wi,           (h16*)(ws + OFF_WI0T));
  k_prep_wt  <<<256, 256, 0, stream>>>(wh,           (h16*)(ws + OFF_WH0T));
  k_prep_wt  <<<256, 256, 0, stream>>>(wi + H_ * H_, (h16*)(ws + OFF_WI1T));
  k_prep_wt  <<<256, 256, 0, stream>>>(wh + H_ * H_, (h16*)(ws + OFF_WH1T));
  k_xp_gemm  <<<4096, 256, 0, stream>>>((const h16*)(ws + OFF_XH),
                                        (const h16*)(ws + OFF_WI0T),
                                        (h16*)(ws + OFF_XP));
  k_scan     <<<256, 256, 0, stream>>>((const h16*)(ws + OFF_WH0T),
                                       (const h16*)(ws + OFF_WI1T),
                                       (const h16*)(ws + OFF_WH1T),
                                       h0,
                                       (const h16*)(ws + OFF_XP),
                                       (const float*)(ws + OFF_B0),
                                       (const float*)(ws + OFF_B1),
                                       (h16*)(ws + OFF_H0S),
                                       (h16*)(ws + OFF_H1S),
                                       out,
                                       (unsigned*)(ws + OFF_AFL),
                                       (unsigned*)(ws + OFF_BFL));
}